// Round 1
// baseline (151.887 us; speedup 1.0000x reference)
//
#include <hip/hip_runtime.h>

#define DD 160
#define HH 192
#define WW 160
#define HW (HH * WW)
#define DHW (DD * HH * WW)
#define NTOT (2 * DHW)

__global__ __launch_bounds__(256) void st_kernel(
    const float* __restrict__ src,
    const float* __restrict__ flow,
    float* __restrict__ out)
{
    int idx = blockIdx.x * 256 + threadIdx.x;
    if (idx >= NTOT) return;

    int n  = idx / DHW;
    int r  = idx - n * DHW;
    int z  = r / HW;
    int r2 = r - z * HW;
    int y  = r2 / WW;
    int x  = r2 - y * WW;

    const float* fb = flow + (size_t)n * 3 * DHW + r;
    float fx = fb[0];
    float fy = fb[DHW];
    float fz = fb[2 * DHW];

    // pixel-space sample coords
    float ix = fmaf(fx, (float)WW * 0.5f, (float)x);
    float iy = fmaf(fy, (float)HH * 0.5f, (float)y);
    float iz = fmaf(fz, (float)DD * 0.5f, (float)z);

    float ix0f = floorf(ix), iy0f = floorf(iy), iz0f = floorf(iz);
    float tx = ix - ix0f, ty = iy - iy0f, tz = iz - iz0f;
    int ix0 = (int)ix0f, iy0 = (int)iy0f, iz0 = (int)iz0f;
    int ix1 = ix0 + 1, iy1 = iy0 + 1, iz1 = iz0 + 1;

    // validity + clamped indices
    bool vx0 = (ix0 >= 0) & (ix0 < WW);
    bool vx1 = (ix1 >= 0) & (ix1 < WW);
    bool vy0 = (iy0 >= 0) & (iy0 < HH);
    bool vy1 = (iy1 >= 0) & (iy1 < HH);
    bool vz0 = (iz0 >= 0) & (iz0 < DD);
    bool vz1 = (iz1 >= 0) & (iz1 < DD);

    int cx0 = min(max(ix0, 0), WW - 1);
    int cx1 = min(max(ix1, 0), WW - 1);
    int cy0 = min(max(iy0, 0), HH - 1);
    int cy1 = min(max(iy1, 0), HH - 1);
    int cz0 = min(max(iz0, 0), DD - 1);
    int cz1 = min(max(iz1, 0), DD - 1);

    const float* sb = src + (size_t)n * DHW;

    float wx0 = 1.0f - tx, wx1 = tx;
    float wy0 = 1.0f - ty, wy1 = ty;
    float wz0 = 1.0f - tz, wz1 = tz;

    float acc = 0.0f;

    // z0 plane
    if (vz0) {
        int zb = cz0 * HW;
        if (vy0) {
            int yb = zb + cy0 * WW;
            float wzy = wz0 * wy0;
            if (vx0) acc = fmaf(sb[yb + cx0], wzy * wx0, acc);
            if (vx1) acc = fmaf(sb[yb + cx1], wzy * wx1, acc);
        }
        if (vy1) {
            int yb = zb + cy1 * WW;
            float wzy = wz0 * wy1;
            if (vx0) acc = fmaf(sb[yb + cx0], wzy * wx0, acc);
            if (vx1) acc = fmaf(sb[yb + cx1], wzy * wx1, acc);
        }
    }
    // z1 plane
    if (vz1) {
        int zb = cz1 * HW;
        if (vy0) {
            int yb = zb + cy0 * WW;
            float wzy = wz1 * wy0;
            if (vx0) acc = fmaf(sb[yb + cx0], wzy * wx0, acc);
            if (vx1) acc = fmaf(sb[yb + cx1], wzy * wx1, acc);
        }
        if (vy1) {
            int yb = zb + cy1 * WW;
            float wzy = wz1 * wy1;
            if (vx0) acc = fmaf(sb[yb + cx0], wzy * wx0, acc);
            if (vx1) acc = fmaf(sb[yb + cx1], wzy * wx1, acc);
        }
    }

    out[idx] = acc;
}

extern "C" void kernel_launch(void* const* d_in, const int* in_sizes, int n_in,
                              void* d_out, int out_size, void* d_ws, size_t ws_size,
                              hipStream_t stream) {
    const float* src  = (const float*)d_in[0];
    const float* flow = (const float*)d_in[1];
    float* out = (float*)d_out;
    int blocks = (NTOT + 255) / 256;
    st_kernel<<<blocks, 256, 0, stream>>>(src, flow, out);
}